// Round 1
// baseline (574.545 us; speedup 1.0000x reference)
//
#include <hip/hip_runtime.h>
#include <cstdint>
#include <cstddef>

// Problem constants (fixed by the reference setup)
#define NNODES 2000
#define TSTEPS 8
#define NHEADS 4
#define CAP    96      // max neighbors per row; degree ~ Binom(2000,0.01)+self ≈ 21±4.5, 96 is >16σ

// ---------------------------------------------------------------------------
// Init: copy q1 -> Q1, q2 -> Q2 (hidden states must be re-seeded every call)
__global__ void init_q_kernel(const float* __restrict__ q1, const float* __restrict__ q2,
                              float* __restrict__ Q1, float* __restrict__ Q2) {
    int i = blockIdx.x * 256 + threadIdx.x;
    if (i < NNODES * 64) Q1[i] = q1[i];
    if (i < NNODES * 32) Q2[i] = q2[i];
}

// ---------------------------------------------------------------------------
// CSR build: one wave per (t,n) row; ballot-compaction keeps neighbor order
// ascending and fully deterministic (no atomics).
__global__ void csr_build_kernel(const float* __restrict__ A, int* __restrict__ nbr,
                                 int* __restrict__ cnt) {
    const int row = blockIdx.x;              // t*N + n
    const float* Ar = A + (size_t)row * NNODES;
    const int lane = threadIdx.x;            // 64 lanes
    int* out = nbr + (size_t)row * CAP;
    int c = 0;
    for (int j0 = 0; j0 < NNODES; j0 += 64) {
        int j = j0 + lane;
        bool p = (j < NNODES) && (Ar[j] > 0.0f);
        unsigned long long m = __ballot(p);
        int off = __popcll(m & ((1ull << lane) - 1ull));
        if (p) { int pos = c + off; if (pos < CAP) out[pos] = j; }
        c += (int)__popcll(m);
    }
    if (lane == 0) cnt[row] = (c > CAP ? CAP : c);
}

// ---------------------------------------------------------------------------
// GAT stage 1: h[h,n,d] = sum_f x[n,f] W[h,f,d]; e_src/e_dst via in-wave reduce.
// Block = H*D threads, one block per node.
template<int F, int D>
__global__ void gat_h_kernel(const float* __restrict__ x, const float* __restrict__ W,
                             const float* __restrict__ a, float* __restrict__ hbuf,
                             float* __restrict__ es, float* __restrict__ ed) {
    const int n = blockIdx.x;
    const int tid = threadIdx.x;             // NHEADS*D
    const int h = tid / D, d = tid % D;
    const float* xr = x + (size_t)n * F;
    const float* Wp = W + (size_t)h * F * D + d;   // W[h][f][d], stride D over f
    float acc = 0.f;
    #pragma unroll 8
    for (int f = 0; f < F; ++f) acc += xr[f] * Wp[(size_t)f * D];
    hbuf[((size_t)h * NNODES + n) * D + d] = acc;
    float s0 = acc * a[(h * 2 + 0) * D + d];
    float s1 = acc * a[(h * 2 + 1) * D + d];
    #pragma unroll
    for (int s = D / 2; s > 0; s >>= 1) {
        s0 += __shfl_down(s0, s, D);
        s1 += __shfl_down(s1, s, D);
    }
    if (d == 0) { es[(size_t)h * NNODES + n] = s0; ed[(size_t)h * NNODES + n] = s1; }
}

// ---------------------------------------------------------------------------
// GAT stage 2: sparse masked softmax + aggregate over neighbors.
// exp(-1e9 - max) == 0 in f32, so iterating only true neighbors is exact.
// Block = H*D threads per node; thread (h,d) owns output element o[h,n,d].
template<int D, bool CONCAT>
__global__ void gat_attn_kernel(const int* __restrict__ nbr, const int* __restrict__ cnt_arr,
                                const float* __restrict__ hbuf, const float* __restrict__ es,
                                const float* __restrict__ ed, float* __restrict__ Z) {
    const int n = blockIdx.x, tid = threadIdx.x;
    const int h = tid / D, d = tid % D;
    const int cnt = cnt_arr[n];
    const int* idx = nbr + (size_t)n * CAP;
    __shared__ int mlist[CAP];
    __shared__ float eds[NHEADS][CAP];
    for (int k = tid; k < cnt; k += NHEADS * D) mlist[k] = idx[k];
    __syncthreads();
    for (int k = d; k < cnt; k += D) eds[h][k] = ed[(size_t)h * NNODES + mlist[k]];
    __syncthreads();
    const float esv = es[(size_t)h * NNODES + n];
    float maxv = -1e30f;
    for (int k = 0; k < cnt; ++k) {
        float v = esv + eds[h][k];
        v = v > 0.f ? v : 0.2f * v;          // leaky_relu(0.2)
        maxv = fmaxf(maxv, v);
    }
    float wsum = 0.f, acc = 0.f;
    for (int k = 0; k < cnt; ++k) {
        float v = esv + eds[h][k];
        v = v > 0.f ? v : 0.2f * v;
        float w = __expf(v - maxv);
        wsum += w;
        acc += w * hbuf[((size_t)h * NNODES + mlist[k]) * D + d];
    }
    float o = acc / wsum;
    if constexpr (CONCAT) {
        float e = o > 0.f ? o : (__expf(o) - 1.0f);   // elu
        Z[(size_t)n * (NHEADS * D) + h * D + d] = e;  // [N, H*D] concat
    } else {
        __shared__ float red[NHEADS][D];
        red[h][d] = o;
        __syncthreads();
        if (h == 0) Z[(size_t)n * D + d] =
            (red[0][d] + red[1][d] + red[2][d] + red[3][d]) * 0.25f;  // mean heads, no elu
    }
}

// ---------------------------------------------------------------------------
// Per-node GRU. matvec: 256 threads read matrix as float4 fully coalesced,
// partial dots reduced across CH=D/4 contiguous lanes via shfl.
template<int D>
__device__ inline void matvec(const float* __restrict__ M, const float* __restrict__ v,
                              float* __restrict__ out, int tid) {
    constexpr int CH = D / 4;                // float4 chunks per row
    constexpr int TOT = D * CH;              // total float4 in matrix
    const float4* M4 = reinterpret_cast<const float4*>(M);
    for (int idx = tid; idx < TOT; idx += 256) {
        float4 m = M4[idx];
        int c = idx & (CH - 1);
        const float* vv = v + (c << 2);
        float p = m.x * vv[0] + m.y * vv[1] + m.z * vv[2] + m.w * vv[3];
        #pragma unroll
        for (int s = CH / 2; s > 0; s >>= 1) p += __shfl_down(p, s, CH);
        if ((tid & (CH - 1)) == 0) out[idx / CH] = p;
    }
}

template<int D>
__global__ void gru_kernel(const float* __restrict__ Wg, const float* __restrict__ Ug,
                           const float* __restrict__ bg, const float* __restrict__ Zin,
                           float* __restrict__ Q, float* __restrict__ outp) {
    const int n = blockIdx.x, tid = threadIdx.x;   // 256 threads
    __shared__ float Zs[D], Qs[D], rq[D], w0[D], w1[D], w2[D], u0[D], u1[D], u2[D], updv[D];
    for (int i = tid; i < D; i += 256) { Zs[i] = Zin[(size_t)n * D + i]; Qs[i] = Q[(size_t)n * D + i]; }
    __syncthreads();
    const size_t MS = (size_t)D * D;
    const size_t NB = NNODES;
    matvec<D>(Wg + ((size_t)0 * NB + n) * MS, Zs, w0, tid);
    matvec<D>(Wg + ((size_t)1 * NB + n) * MS, Zs, w1, tid);
    matvec<D>(Wg + ((size_t)2 * NB + n) * MS, Zs, w2, tid);
    matvec<D>(Ug + ((size_t)0 * NB + n) * MS, Qs, u0, tid);
    matvec<D>(Ug + ((size_t)1 * NB + n) * MS, Qs, u1, tid);
    __syncthreads();
    for (int i = tid; i < D; i += 256) {
        float b0 = bg[((size_t)0 * NB + n) * D + i];
        float b1 = bg[((size_t)1 * NB + n) * D + i];
        float upd = 1.f / (1.f + __expf(-(w0[i] + b0 + u0[i])));
        float rst = 1.f / (1.f + __expf(-(w1[i] + b1 + u1[i])));
        updv[i] = upd;
        rq[i] = rst * Qs[i];
    }
    __syncthreads();
    matvec<D>(Ug + ((size_t)2 * NB + n) * MS, rq, u2, tid);
    __syncthreads();
    for (int i = tid; i < D; i += 256) {
        float b2 = bg[((size_t)2 * NB + n) * D + i];
        float hcap = tanhf(w2[i] + b2 + u2[i]);
        float qn = (1.f - updv[i]) * Qs[i] + updv[i] * hcap;
        Q[(size_t)n * D + i] = qn;           // in-place: node n only touched by block n
        outp[(size_t)n * D + i] = qn;
    }
}

// ---------------------------------------------------------------------------
extern "C" void kernel_launch(void* const* d_in, const int* in_sizes, int n_in,
                              void* d_out, int out_size, void* d_ws, size_t ws_size,
                              hipStream_t stream) {
    const float* A      = (const float*)d_in[0];
    const float* feats  = (const float*)d_in[1];
    const float* gat1_W = (const float*)d_in[2];
    const float* gat1_a = (const float*)d_in[3];
    const float* gru1_W = (const float*)d_in[4];
    const float* gru1_U = (const float*)d_in[5];
    const float* gru1_b = (const float*)d_in[6];
    const float* q1     = (const float*)d_in[7];
    const float* gat2_W = (const float*)d_in[8];
    const float* gat2_a = (const float*)d_in[9];
    const float* gru2_W = (const float*)d_in[10];
    const float* gru2_U = (const float*)d_in[11];
    const float* gru2_b = (const float*)d_in[12];
    const float* q2     = (const float*)d_in[13];
    float* out = (float*)d_out;

    // Workspace layout (~12.2 MB total)
    char* ws = (char*)d_ws;
    int*   nbr  = (int*)ws;    ws += (size_t)TSTEPS * NNODES * CAP * 4;
    int*   cnt  = (int*)ws;    ws += (size_t)TSTEPS * NNODES * 4;
    float* hbuf = (float*)ws;  ws += (size_t)NHEADS * NNODES * 32 * 4;
    float* es   = (float*)ws;  ws += (size_t)NHEADS * NNODES * 4;
    float* ed   = (float*)ws;  ws += (size_t)NHEADS * NNODES * 4;
    float* Z1   = (float*)ws;  ws += (size_t)NNODES * 64 * 4;
    float* Z2   = (float*)ws;  ws += (size_t)NNODES * 32 * 4;
    float* Q1   = (float*)ws;  ws += (size_t)NNODES * 64 * 4;
    float* Q2   = (float*)ws;  ws += (size_t)NNODES * 32 * 4;
    float* s1   = (float*)ws;  ws += (size_t)TSTEPS * NNODES * 64 * 4;

    init_q_kernel<<<(NNODES * 64 + 255) / 256, 256, 0, stream>>>(q1, q2, Q1, Q2);
    csr_build_kernel<<<TSTEPS * NNODES, 64, 0, stream>>>(A, nbr, cnt);

    // Layer 1: GAT(concat) + per-node GRU, D=64
    for (int t = 0; t < TSTEPS; ++t) {
        gat_h_kernel<32, 16><<<NNODES, 64, 0, stream>>>(
            feats + (size_t)t * NNODES * 32, gat1_W, gat1_a, hbuf, es, ed);
        gat_attn_kernel<16, true><<<NNODES, 64, 0, stream>>>(
            nbr + (size_t)t * NNODES * CAP, cnt + (size_t)t * NNODES, hbuf, es, ed, Z1);
        gru_kernel<64><<<NNODES, 256, 0, stream>>>(
            gru1_W, gru1_U, gru1_b, Z1, Q1, s1 + (size_t)t * NNODES * 64);
    }
    // Layer 2: GAT(mean) + per-node GRU, D=32; output straight into d_out
    for (int t = 0; t < TSTEPS; ++t) {
        gat_h_kernel<64, 32><<<NNODES, 128, 0, stream>>>(
            s1 + (size_t)t * NNODES * 64, gat2_W, gat2_a, hbuf, es, ed);
        gat_attn_kernel<32, false><<<NNODES, 128, 0, stream>>>(
            nbr + (size_t)t * NNODES * CAP, cnt + (size_t)t * NNODES, hbuf, es, ed, Z2);
        gru_kernel<32><<<NNODES, 256, 0, stream>>>(
            gru2_W, gru2_U, gru2_b, Z2, Q2, out + (size_t)t * NNODES * 32);
    }
}

// Round 2
// 272.325 us; speedup vs baseline: 2.1098x; 2.1098x over previous
//
#include <hip/hip_runtime.h>
#include <cstdint>
#include <cstddef>

// Problem constants (fixed by the reference setup)
#define NNODES 2000
#define TSTEPS 8
#define NHEADS 4
#define CAP    96      // max neighbors; degree ~ Binom(2000,0.01)+self ≈ 21±4.5, 96 is >16σ

// ---------------------------------------------------------------------------
// CSR build: one wave per (t,n) row; ballot-compaction keeps neighbor order
// ascending and fully deterministic (no atomics).
__global__ void csr_build_kernel(const float* __restrict__ A, int* __restrict__ nbr,
                                 int* __restrict__ cnt) {
    const int row = blockIdx.x;              // t*N + n
    const float* Ar = A + (size_t)row * NNODES;
    const int lane = threadIdx.x;            // 64 lanes
    int* out = nbr + (size_t)row * CAP;
    int c = 0;
    for (int j0 = 0; j0 < NNODES; j0 += 64) {
        int j = j0 + lane;
        bool p = (j < NNODES) && (Ar[j] > 0.0f);
        unsigned long long m = __ballot(p);
        int off = __popcll(m & ((1ull << lane) - 1ull));
        if (p) { int pos = c + off; if (pos < CAP) out[pos] = j; }
        c += (int)__popcll(m);
    }
    if (lane == 0) cnt[row] = (c > CAP ? CAP : c);
}

// ---------------------------------------------------------------------------
// GAT stage 1, ALL timesteps: h[t,h,n,d] = sum_f x[t,n,f] W[h,f,d]; es/ed reduced in-wave.
// Grid = T*N blocks, block = H*D threads.
template<int F, int D>
__global__ void gat_h_all_kernel(const float* __restrict__ x, const float* __restrict__ W,
                                 const float* __restrict__ a, float* __restrict__ hbuf,
                                 float* __restrict__ es, float* __restrict__ ed) {
    const int b = blockIdx.x;                // t*N + n
    const int t = b / NNODES, n = b % NNODES;
    const int tid = threadIdx.x;             // NHEADS*D
    const int h = tid / D, d = tid % D;
    const float* xr = x + (size_t)b * F;     // x is [T][N][F] contiguous
    const float* Wp = W + (size_t)h * F * D + d;
    float acc = 0.f;
    #pragma unroll 8
    for (int f = 0; f < F; ++f) acc += xr[f] * Wp[(size_t)f * D];
    hbuf[(((size_t)t * NHEADS + h) * NNODES + n) * D + d] = acc;
    float s0 = acc * a[(h * 2 + 0) * D + d];
    float s1 = acc * a[(h * 2 + 1) * D + d];
    #pragma unroll
    for (int s = D / 2; s > 0; s >>= 1) {
        s0 += __shfl_down(s0, s, D);
        s1 += __shfl_down(s1, s, D);
    }
    if (d == 0) {
        es[((size_t)t * NHEADS + h) * NNODES + n] = s0;
        ed[((size_t)t * NHEADS + h) * NNODES + n] = s1;
    }
}

// ---------------------------------------------------------------------------
// GAT stage 2, ALL timesteps: sparse masked softmax + aggregate (exact: masked
// entries give exp(-1e9-max)==0 in f32). Grid = T*N blocks, block = H*D.
template<int D, bool CONCAT>
__global__ void gat_attn_all_kernel(const int* __restrict__ nbr, const int* __restrict__ cnt_arr,
                                    const float* __restrict__ hbuf, const float* __restrict__ es,
                                    const float* __restrict__ ed, float* __restrict__ Z) {
    const int b = blockIdx.x;
    const int t = b / NNODES;
    const int tid = threadIdx.x;
    const int h = tid / D, d = tid % D;
    const int cnt = cnt_arr[b];
    const int* idx = nbr + (size_t)b * CAP;
    const float* esb = es + (size_t)t * NHEADS * NNODES;
    const float* edb = ed + (size_t)t * NHEADS * NNODES;
    const float* hb  = hbuf + (size_t)t * NHEADS * NNODES * D;
    const int n = b % NNODES;
    __shared__ int mlist[CAP];
    __shared__ float eds[NHEADS][CAP];
    for (int k = tid; k < cnt; k += NHEADS * D) mlist[k] = idx[k];
    __syncthreads();
    for (int k = d; k < cnt; k += D) eds[h][k] = edb[(size_t)h * NNODES + mlist[k]];
    __syncthreads();
    const float esv = esb[(size_t)h * NNODES + n];
    float maxv = -1e30f;
    for (int k = 0; k < cnt; ++k) {
        float v = esv + eds[h][k];
        v = v > 0.f ? v : 0.2f * v;          // leaky_relu(0.2)
        maxv = fmaxf(maxv, v);
    }
    float wsum = 0.f, acc = 0.f;
    for (int k = 0; k < cnt; ++k) {
        float v = esv + eds[h][k];
        v = v > 0.f ? v : 0.2f * v;
        float w = __expf(v - maxv);
        wsum += w;
        acc += w * hb[((size_t)h * NNODES + mlist[k]) * D + d];
    }
    float o = acc / wsum;
    if constexpr (CONCAT) {
        float e = o > 0.f ? o : (__expf(o) - 1.0f);       // elu
        Z[(size_t)b * (NHEADS * D) + h * D + d] = e;      // [T][N][H*D]
    } else {
        __shared__ float red[NHEADS][D];
        red[h][d] = o;
        __syncthreads();
        if (h == 0) Z[(size_t)b * D + d] =
            (red[0][d] + red[1][d] + red[2][d] + red[3][d]) * 0.25f;  // mean heads, no elu
    }
}

// ---------------------------------------------------------------------------
// Precompute wz[n][g][t][i] = sum_j W[g,n,i,j] * Z[t,n,j] + b[g,n,i] for ALL t.
// Reads gru_W exactly once (8-vector reuse per matrix element).
// Grid = N blocks, 256 threads.
template<int D>
__global__ void wz_kernel(const float* __restrict__ Wg, const float* __restrict__ bg,
                          const float* __restrict__ Z, float* __restrict__ wz) {
    constexpr int CH = D / 4;                // float4 chunks per row (16 or 8)
    constexpr int CHS = (D == 64) ? 4 : 3;   // log2(CH)
    constexpr int F4PM = D * CH;             // float4 per matrix
    constexpr int KPT = F4PM / 256;          // float4 per thread per matrix
    const int n = blockIdx.x, tid = threadIdx.x;
    __shared__ float Zs[TSTEPS][D];
    __shared__ float bgs[3][D];
    __shared__ float wl[3][TSTEPS][D + 1];   // +1 pad: avoid same-bank t-stride writes
    for (int idx = tid; idx < TSTEPS * D; idx += 256) {
        int t = idx / D, i = idx % D;
        Zs[t][i] = Z[((size_t)t * NNODES + n) * D + i];
    }
    for (int idx = tid; idx < 3 * D; idx += 256) {
        int g = idx / D, i = idx % D;
        bgs[g][i] = bg[((size_t)g * NNODES + n) * D + i];
    }
    __syncthreads();
    const int chunk = tid & (CH - 1);
    const int c4 = chunk * 4;
    #pragma unroll
    for (int g = 0; g < 3; ++g) {
        const float4* W4 = reinterpret_cast<const float4*>(Wg + ((size_t)g * NNODES + n) * D * D);
        #pragma unroll
        for (int kk = 0; kk < KPT; ++kk) {
            int j = kk * 256 + tid;
            int row = j >> CHS;
            float4 m = W4[j];
            float p[TSTEPS];
            #pragma unroll
            for (int t = 0; t < TSTEPS; ++t)
                p[t] = m.x * Zs[t][c4] + m.y * Zs[t][c4 + 1] + m.z * Zs[t][c4 + 2] + m.w * Zs[t][c4 + 3];
            #pragma unroll
            for (int t = 0; t < TSTEPS; ++t) {
                #pragma unroll
                for (int s = CH / 2; s > 0; s >>= 1) p[t] += __shfl_xor(p[t], s, CH);
            }
            #pragma unroll
            for (int t = 0; t < TSTEPS; ++t)
                if (chunk == t) wl[g][t][row] = p[t];   // compile-time index into p[]
        }
    }
    __syncthreads();
    for (int idx = tid; idx < 3 * TSTEPS * D; idx += 256) {
        int g = idx / (TSTEPS * D), r = idx % (TSTEPS * D), t = r / D, i = r % D;
        wz[((size_t)n * 3 * TSTEPS + g * TSTEPS + t) * D + i] = wl[g][t][i] + bgs[g][i];
    }
}

// ---------------------------------------------------------------------------
// Persistent per-node GRU over ALL timesteps. U matrices register-resident
// (read from HBM exactly once); Q lives in LDS. Grid = N blocks, 256 threads.
template<int D>
__global__ void gru_all_kernel(const float* __restrict__ Ug, const float* __restrict__ wz,
                               const float* __restrict__ q0, float* __restrict__ outp) {
    constexpr int CH = D / 4;
    constexpr int CHS = (D == 64) ? 4 : 3;
    constexpr int F4PM = D * CH;
    constexpr int KPT = F4PM / 256;
    const int n = blockIdx.x, tid = threadIdx.x;
    __shared__ float Qs[D], rq[D], u0[D], u1[D], u2[D], upd[D];
    float4 u[3][KPT];
    #pragma unroll
    for (int g = 0; g < 3; ++g) {
        const float4* U4 = reinterpret_cast<const float4*>(Ug + ((size_t)g * NNODES + n) * D * D);
        #pragma unroll
        for (int kk = 0; kk < KPT; ++kk) u[g][kk] = U4[kk * 256 + tid];
    }
    for (int i = tid; i < D; i += 256) Qs[i] = q0[(size_t)n * D + i];
    __syncthreads();
    const int chunk = tid & (CH - 1);
    const int c4 = chunk * 4;
    const float* wzn = wz + (size_t)n * 3 * TSTEPS * D;
    for (int t = 0; t < TSTEPS; ++t) {
        // u0 = U0·Q, u1 = U1·Q (from registers)
        #pragma unroll
        for (int kk = 0; kk < KPT; ++kk) {
            int row = (kk * 256 + tid) >> CHS;
            float q0v = Qs[c4], q1v = Qs[c4 + 1], q2v = Qs[c4 + 2], q3v = Qs[c4 + 3];
            float p0 = u[0][kk].x * q0v + u[0][kk].y * q1v + u[0][kk].z * q2v + u[0][kk].w * q3v;
            float p1 = u[1][kk].x * q0v + u[1][kk].y * q1v + u[1][kk].z * q2v + u[1][kk].w * q3v;
            #pragma unroll
            for (int s = CH / 2; s > 0; s >>= 1) {
                p0 += __shfl_xor(p0, s, CH);
                p1 += __shfl_xor(p1, s, CH);
            }
            if (chunk == 0) { u0[row] = p0; u1[row] = p1; }
        }
        __syncthreads();
        if (tid < D) {
            float z = 1.f / (1.f + __expf(-(wzn[(0 * TSTEPS + t) * D + tid] + u0[tid])));
            float r = 1.f / (1.f + __expf(-(wzn[(1 * TSTEPS + t) * D + tid] + u1[tid])));
            upd[tid] = z;
            rq[tid] = r * Qs[tid];
        }
        __syncthreads();
        // u2 = U2·(rst*Q)
        #pragma unroll
        for (int kk = 0; kk < KPT; ++kk) {
            int row = (kk * 256 + tid) >> CHS;
            float p = u[2][kk].x * rq[c4] + u[2][kk].y * rq[c4 + 1]
                    + u[2][kk].z * rq[c4 + 2] + u[2][kk].w * rq[c4 + 3];
            #pragma unroll
            for (int s = CH / 2; s > 0; s >>= 1) p += __shfl_xor(p, s, CH);
            if (chunk == 0) u2[row] = p;
        }
        __syncthreads();
        if (tid < D) {
            float hcap = tanhf(wzn[(2 * TSTEPS + t) * D + tid] + u2[tid]);
            float z = upd[tid];
            float qn = (1.f - z) * Qs[tid] + z * hcap;
            outp[((size_t)t * NNODES + n) * D + tid] = qn;
            Qs[tid] = qn;
        }
        __syncthreads();
    }
}

// ---------------------------------------------------------------------------
extern "C" void kernel_launch(void* const* d_in, const int* in_sizes, int n_in,
                              void* d_out, int out_size, void* d_ws, size_t ws_size,
                              hipStream_t stream) {
    const float* A      = (const float*)d_in[0];
    const float* feats  = (const float*)d_in[1];
    const float* gat1_W = (const float*)d_in[2];
    const float* gat1_a = (const float*)d_in[3];
    const float* gru1_W = (const float*)d_in[4];
    const float* gru1_U = (const float*)d_in[5];
    const float* gru1_b = (const float*)d_in[6];
    const float* q1     = (const float*)d_in[7];
    const float* gat2_W = (const float*)d_in[8];
    const float* gat2_a = (const float*)d_in[9];
    const float* gru2_W = (const float*)d_in[10];
    const float* gru2_U = (const float*)d_in[11];
    const float* gru2_b = (const float*)d_in[12];
    const float* q2     = (const float*)d_in[13];
    float* out = (float*)d_out;

    // Workspace layout (~48 MB)
    char* ws = (char*)d_ws;
    int*   nbr  = (int*)ws;    ws += (size_t)TSTEPS * NNODES * CAP * 4;
    int*   cnt  = (int*)ws;    ws += (size_t)TSTEPS * NNODES * 4;
    float* h1   = (float*)ws;  ws += (size_t)TSTEPS * NHEADS * NNODES * 16 * 4;
    float* es1  = (float*)ws;  ws += (size_t)TSTEPS * NHEADS * NNODES * 4;
    float* ed1  = (float*)ws;  ws += (size_t)TSTEPS * NHEADS * NNODES * 4;
    float* Z1   = (float*)ws;  ws += (size_t)TSTEPS * NNODES * 64 * 4;
    float* wz1  = (float*)ws;  ws += (size_t)NNODES * 3 * TSTEPS * 64 * 4;
    float* s1   = (float*)ws;  ws += (size_t)TSTEPS * NNODES * 64 * 4;
    float* h2   = (float*)ws;  ws += (size_t)TSTEPS * NHEADS * NNODES * 32 * 4;
    float* es2  = (float*)ws;  ws += (size_t)TSTEPS * NHEADS * NNODES * 4;
    float* ed2  = (float*)ws;  ws += (size_t)TSTEPS * NHEADS * NNODES * 4;
    float* Z2   = (float*)ws;  ws += (size_t)TSTEPS * NNODES * 32 * 4;
    float* wz2  = (float*)ws;  ws += (size_t)NNODES * 3 * TSTEPS * 32 * 4;

    csr_build_kernel<<<TSTEPS * NNODES, 64, 0, stream>>>(A, nbr, cnt);

    // Layer 1 (concat, D1=64): all-t GAT -> all-t W·Z -> persistent per-node GRU
    gat_h_all_kernel<32, 16><<<TSTEPS * NNODES, 64, 0, stream>>>(feats, gat1_W, gat1_a, h1, es1, ed1);
    gat_attn_all_kernel<16, true><<<TSTEPS * NNODES, 64, 0, stream>>>(nbr, cnt, h1, es1, ed1, Z1);
    wz_kernel<64><<<NNODES, 256, 0, stream>>>(gru1_W, gru1_b, Z1, wz1);
    gru_all_kernel<64><<<NNODES, 256, 0, stream>>>(gru1_U, wz1, q1, s1);

    // Layer 2 (mean, D2=32): same pipeline, output straight into d_out
    gat_h_all_kernel<64, 32><<<TSTEPS * NNODES, 128, 0, stream>>>(s1, gat2_W, gat2_a, h2, es2, ed2);
    gat_attn_all_kernel<32, false><<<TSTEPS * NNODES, 128, 0, stream>>>(nbr, cnt, h2, es2, ed2, Z2);
    wz_kernel<32><<<NNODES, 256, 0, stream>>>(gru2_W, gru2_b, Z2, wz2);
    gru_all_kernel<32><<<NNODES, 256, 0, stream>>>(gru2_U, wz2, q2, out);
}

// Round 3
// 248.000 us; speedup vs baseline: 2.3167x; 1.0981x over previous
//
#include <hip/hip_runtime.h>
#include <cstdint>
#include <cstddef>

// Problem constants (fixed by the reference setup)
#define NNODES 2000
#define TSTEPS 8
#define NHEADS 4
#define CAP    96      // max neighbors; degree ~ Binom(2000,0.01)+self ≈ 21±4.5, 96 is >16σ
#define NROWS  (TSTEPS * NNODES)   // 16000

// ---------------------------------------------------------------------------
// K1: blocks [0,NROWS) build CSR rows (ballot-compaction, deterministic order);
//     blocks [NROWS,2*NROWS) compute layer-1 GAT projection h1/es1/ed1.
// Both use 64-thread blocks; the tiny projection hides under the HBM A-scan.
__global__ void k1_csr_gath1(const float* __restrict__ A,
                             int* __restrict__ nbr, int* __restrict__ cnt,
                             const float* __restrict__ feats,
                             const float* __restrict__ W, const float* __restrict__ a,
                             float* __restrict__ hbuf, float* __restrict__ es,
                             float* __restrict__ ed) {
    const int lane = threadIdx.x;            // 64
    if (blockIdx.x < NROWS) {
        const int row = blockIdx.x;          // t*N + n
        const float* Ar = A + (size_t)row * NNODES;
        int* outp = nbr + (size_t)row * CAP;
        int c = 0;
        for (int j0 = 0; j0 < NNODES; j0 += 64) {
            int j = j0 + lane;
            bool p = (j < NNODES) && (Ar[j] > 0.0f);
            unsigned long long m = __ballot(p);
            int off = __popcll(m & ((1ull << lane) - 1ull));
            if (p) { int pos = c + off; if (pos < CAP) outp[pos] = j; }
            c += (int)__popcll(m);
        }
        if (lane == 0) cnt[row] = (c > CAP ? CAP : c);
    } else {
        const int b = blockIdx.x - NROWS;    // t*N + n
        const int t = b / NNODES, n = b % NNODES;
        constexpr int F = 32, D = 16;
        const int h = lane / D, d = lane % D;
        const float* xr = feats + (size_t)b * F;
        const float* Wp = W + (size_t)h * F * D + d;
        float acc = 0.f;
        #pragma unroll
        for (int f = 0; f < F; ++f) acc += xr[f] * Wp[f * D];
        hbuf[(((size_t)t * NHEADS + h) * NNODES + n) * D + d] = acc;
        float s0 = acc * a[(h * 2 + 0) * D + d];
        float s1 = acc * a[(h * 2 + 1) * D + d];
        #pragma unroll
        for (int s = D / 2; s > 0; s >>= 1) {
            s0 += __shfl_down(s0, s, D);
            s1 += __shfl_down(s1, s, D);
        }
        if (d == 0) {
            es[((size_t)t * NHEADS + h) * NNODES + n] = s0;
            ed[((size_t)t * NHEADS + h) * NNODES + n] = s1;
        }
    }
}

// ---------------------------------------------------------------------------
// Layer-2 GAT projection for all t (needs full s1). Grid = NROWS, block = 128.
template<int F, int D>
__global__ void gat_h_all_kernel(const float* __restrict__ x, const float* __restrict__ W,
                                 const float* __restrict__ a, float* __restrict__ hbuf,
                                 float* __restrict__ es, float* __restrict__ ed) {
    const int b = blockIdx.x;                // t*N + n
    const int t = b / NNODES, n = b % NNODES;
    const int tid = threadIdx.x;             // NHEADS*D
    const int h = tid / D, d = tid % D;
    const float* xr = x + (size_t)b * F;
    const float* Wp = W + (size_t)h * F * D + d;
    float acc = 0.f;
    #pragma unroll
    for (int f = 0; f < F; ++f) acc += xr[f] * Wp[f * D];
    hbuf[(((size_t)t * NHEADS + h) * NNODES + n) * D + d] = acc;
    float s0 = acc * a[(h * 2 + 0) * D + d];
    float s1 = acc * a[(h * 2 + 1) * D + d];
    #pragma unroll
    for (int s = D / 2; s > 0; s >>= 1) {
        s0 += __shfl_down(s0, s, D);
        s1 += __shfl_down(s1, s, D);
    }
    if (d == 0) {
        es[((size_t)t * NHEADS + h) * NNODES + n] = s0;
        ed[((size_t)t * NHEADS + h) * NNODES + n] = s1;
    }
}

// ---------------------------------------------------------------------------
// Sparse masked softmax + aggregate, all t (exact: masked entries give
// exp(-1e9-max)==0 in f32). Grid = NROWS, block = H*D.
template<int D, bool CONCAT>
__global__ void gat_attn_all_kernel(const int* __restrict__ nbr, const int* __restrict__ cnt_arr,
                                    const float* __restrict__ hbuf, const float* __restrict__ es,
                                    const float* __restrict__ ed, float* __restrict__ Z) {
    const int b = blockIdx.x;
    const int t = b / NNODES, n = b % NNODES;
    const int tid = threadIdx.x;
    const int h = tid / D, d = tid % D;
    const int cnt = cnt_arr[b];
    const int* idx = nbr + (size_t)b * CAP;
    const float* esb = es + (size_t)t * NHEADS * NNODES;
    const float* edb = ed + (size_t)t * NHEADS * NNODES;
    const float* hb  = hbuf + (size_t)t * NHEADS * NNODES * D;
    __shared__ int mlist[CAP];
    __shared__ float eds[NHEADS][CAP];
    for (int k = tid; k < cnt; k += NHEADS * D) mlist[k] = idx[k];
    __syncthreads();
    for (int k = d; k < cnt; k += D) eds[h][k] = edb[(size_t)h * NNODES + mlist[k]];
    __syncthreads();
    const float esv = esb[(size_t)h * NNODES + n];
    float maxv = -1e30f;
    for (int k = 0; k < cnt; ++k) {
        float v = esv + eds[h][k];
        v = v > 0.f ? v : 0.2f * v;          // leaky_relu(0.2)
        maxv = fmaxf(maxv, v);
    }
    float wsum = 0.f, acc = 0.f;
    for (int k = 0; k < cnt; ++k) {
        float v = esv + eds[h][k];
        v = v > 0.f ? v : 0.2f * v;
        float w = __expf(v - maxv);
        wsum += w;
        acc += w * hb[((size_t)h * NNODES + mlist[k]) * D + d];
    }
    float o = acc / wsum;
    if constexpr (CONCAT) {
        float e = o > 0.f ? o : (__expf(o) - 1.0f);       // elu
        Z[(size_t)b * (NHEADS * D) + h * D + d] = e;      // [T][N][H*D]
    } else {
        __shared__ float red[NHEADS][D];
        red[h][d] = o;
        __syncthreads();
        if (h == 0) Z[(size_t)b * D + d] =
            (red[0][d] + red[1][d] + red[2][d] + red[3][d]) * 0.25f;  // mean heads, no elu
    }
}

// ---------------------------------------------------------------------------
// Fused per-node GRU: stream W -> wz (all t) into LDS, U into registers,
// then run all 8 timesteps. Weights touch HBM exactly once; no wz round-trip.
// Grid = N blocks, 256 threads.
template<int D>
__global__ void wzgru_kernel(const float* __restrict__ Wg, const float* __restrict__ Ug,
                             const float* __restrict__ bg, const float* __restrict__ Z,
                             const float* __restrict__ q0, float* __restrict__ outp) {
    constexpr int CH = D / 4;                // float4 chunks per row (16 or 8)
    constexpr int CHS = (D == 64) ? 4 : 3;   // log2(CH)
    constexpr int F4PM = D * CH;             // float4 per matrix
    constexpr int KPT = F4PM / 256;          // float4 per thread per matrix
    const int n = blockIdx.x, tid = threadIdx.x;
    __shared__ float Zs[TSTEPS][D];
    __shared__ float bgs[3][D];
    __shared__ float wzs[3][TSTEPS][D + 1];  // +1 pad breaks same-bank strides
    __shared__ float Qs[D], rq[D], u0s[D], u1s[D], u2s[D], upds[D];
    for (int idx = tid; idx < TSTEPS * D; idx += 256) {
        int t = idx / D, i = idx % D;
        Zs[t][i] = Z[((size_t)t * NNODES + n) * D + i];
    }
    for (int idx = tid; idx < 3 * D; idx += 256) {
        int g = idx / D, i = idx % D;
        bgs[g][i] = bg[((size_t)g * NNODES + n) * D + i];
    }
    if (tid < D) Qs[tid] = q0[(size_t)n * D + tid];
    __syncthreads();
    const int chunk = tid & (CH - 1);
    const int c4 = chunk * 4;
    // Phase B: wz[g][t][:] = W[g]·Z[t] + b[g]  (stream W, 8-vector reuse)
    #pragma unroll
    for (int g = 0; g < 3; ++g) {
        const float4* W4 = reinterpret_cast<const float4*>(Wg + ((size_t)g * NNODES + n) * D * D);
        #pragma unroll
        for (int kk = 0; kk < KPT; ++kk) {
            int j = kk * 256 + tid;
            int row = j >> CHS;
            float4 m = W4[j];
            float p[TSTEPS];
            #pragma unroll
            for (int t = 0; t < TSTEPS; ++t)
                p[t] = m.x * Zs[t][c4] + m.y * Zs[t][c4 + 1] + m.z * Zs[t][c4 + 2] + m.w * Zs[t][c4 + 3];
            #pragma unroll
            for (int t = 0; t < TSTEPS; ++t) {
                #pragma unroll
                for (int s = CH / 2; s > 0; s >>= 1) p[t] += __shfl_xor(p[t], s, CH);
            }
            #pragma unroll
            for (int t = 0; t < TSTEPS; ++t)
                if (chunk == t) wzs[g][t][row] = p[t] + bgs[g][row];  // static index into p[]
        }
    }
    // Phase C: U into registers (issued before the barrier; waitcnt lands at first use)
    float4 u[3][KPT];
    #pragma unroll
    for (int g = 0; g < 3; ++g) {
        const float4* U4 = reinterpret_cast<const float4*>(Ug + ((size_t)g * NNODES + n) * D * D);
        #pragma unroll
        for (int kk = 0; kk < KPT; ++kk) u[g][kk] = U4[kk * 256 + tid];
    }
    __syncthreads();
    // Phase D: 8 GRU steps, all operands in LDS/registers
    for (int t = 0; t < TSTEPS; ++t) {
        #pragma unroll
        for (int kk = 0; kk < KPT; ++kk) {
            int row = (kk * 256 + tid) >> CHS;
            float q0v = Qs[c4], q1v = Qs[c4 + 1], q2v = Qs[c4 + 2], q3v = Qs[c4 + 3];
            float p0 = u[0][kk].x * q0v + u[0][kk].y * q1v + u[0][kk].z * q2v + u[0][kk].w * q3v;
            float p1 = u[1][kk].x * q0v + u[1][kk].y * q1v + u[1][kk].z * q2v + u[1][kk].w * q3v;
            #pragma unroll
            for (int s = CH / 2; s > 0; s >>= 1) {
                p0 += __shfl_xor(p0, s, CH);
                p1 += __shfl_xor(p1, s, CH);
            }
            if (chunk == 0) { u0s[row] = p0; u1s[row] = p1; }
        }
        __syncthreads();
        if (tid < D) {
            float z = 1.f / (1.f + __expf(-(wzs[0][t][tid] + u0s[tid])));
            float r = 1.f / (1.f + __expf(-(wzs[1][t][tid] + u1s[tid])));
            upds[tid] = z;
            rq[tid] = r * Qs[tid];
        }
        __syncthreads();
        #pragma unroll
        for (int kk = 0; kk < KPT; ++kk) {
            int row = (kk * 256 + tid) >> CHS;
            float p = u[2][kk].x * rq[c4] + u[2][kk].y * rq[c4 + 1]
                    + u[2][kk].z * rq[c4 + 2] + u[2][kk].w * rq[c4 + 3];
            #pragma unroll
            for (int s = CH / 2; s > 0; s >>= 1) p += __shfl_xor(p, s, CH);
            if (chunk == 0) u2s[row] = p;
        }
        __syncthreads();
        if (tid < D) {
            float hcap = tanhf(wzs[2][t][tid] + u2s[tid]);
            float z = upds[tid];
            float qn = (1.f - z) * Qs[tid] + z * hcap;
            outp[((size_t)t * NNODES + n) * D + tid] = qn;
            Qs[tid] = qn;
        }
        __syncthreads();
    }
}

// ---------------------------------------------------------------------------
extern "C" void kernel_launch(void* const* d_in, const int* in_sizes, int n_in,
                              void* d_out, int out_size, void* d_ws, size_t ws_size,
                              hipStream_t stream) {
    const float* A      = (const float*)d_in[0];
    const float* feats  = (const float*)d_in[1];
    const float* gat1_W = (const float*)d_in[2];
    const float* gat1_a = (const float*)d_in[3];
    const float* gru1_W = (const float*)d_in[4];
    const float* gru1_U = (const float*)d_in[5];
    const float* gru1_b = (const float*)d_in[6];
    const float* q1     = (const float*)d_in[7];
    const float* gat2_W = (const float*)d_in[8];
    const float* gat2_a = (const float*)d_in[9];
    const float* gru2_W = (const float*)d_in[10];
    const float* gru2_U = (const float*)d_in[11];
    const float* gru2_b = (const float*)d_in[12];
    const float* q2     = (const float*)d_in[13];
    float* out = (float*)d_out;

    // Workspace layout (~30 MB)
    char* ws = (char*)d_ws;
    int*   nbr  = (int*)ws;    ws += (size_t)NROWS * CAP * 4;
    int*   cnt  = (int*)ws;    ws += (size_t)NROWS * 4;
    float* h1   = (float*)ws;  ws += (size_t)TSTEPS * NHEADS * NNODES * 16 * 4;
    float* es1  = (float*)ws;  ws += (size_t)TSTEPS * NHEADS * NNODES * 4;
    float* ed1  = (float*)ws;  ws += (size_t)TSTEPS * NHEADS * NNODES * 4;
    float* Z1   = (float*)ws;  ws += (size_t)TSTEPS * NNODES * 64 * 4;
    float* s1   = (float*)ws;  ws += (size_t)TSTEPS * NNODES * 64 * 4;
    float* h2   = (float*)ws;  ws += (size_t)TSTEPS * NHEADS * NNODES * 32 * 4;
    float* es2  = (float*)ws;  ws += (size_t)TSTEPS * NHEADS * NNODES * 4;
    float* ed2  = (float*)ws;  ws += (size_t)TSTEPS * NHEADS * NNODES * 4;
    float* Z2   = (float*)ws;  ws += (size_t)TSTEPS * NNODES * 32 * 4;

    // K1: CSR build (HBM-bound A-scan) overlapped with layer-1 GAT projection
    k1_csr_gath1<<<2 * NROWS, 64, 0, stream>>>(A, nbr, cnt, feats, gat1_W, gat1_a,
                                               h1, es1, ed1);
    // K2: layer-1 sparse attention -> Z1
    gat_attn_all_kernel<16, true><<<NROWS, 64, 0, stream>>>(nbr, cnt, h1, es1, ed1, Z1);
    // K3: layer-1 fused wz+GRU -> s1
    wzgru_kernel<64><<<NNODES, 256, 0, stream>>>(gru1_W, gru1_U, gru1_b, Z1, q1, s1);
    // K4: layer-2 GAT projection
    gat_h_all_kernel<64, 32><<<NROWS, 128, 0, stream>>>(s1, gat2_W, gat2_a, h2, es2, ed2);
    // K5: layer-2 sparse attention -> Z2
    gat_attn_all_kernel<32, false><<<NROWS, 128, 0, stream>>>(nbr, cnt, h2, es2, ed2, Z2);
    // K6: layer-2 fused wz+GRU -> out
    wzgru_kernel<32><<<NNODES, 256, 0, stream>>>(gru2_W, gru2_U, gru2_b, Z2, q2, out);
}

// Round 4
// 186.776 us; speedup vs baseline: 3.0761x; 1.3278x over previous
//
#include <hip/hip_runtime.h>
#include <cstdint>
#include <cstddef>

// Problem constants (fixed by the reference setup)
#define NNODES 2000
#define TSTEPS 8
#define NHEADS 4
#define CAP    96      // max neighbors; degree ~ Binom(2000,0.01)+self ≈ 21±4.5, 96 is >16σ
#define NROWS  (TSTEPS * NNODES)   // 16000

// ---------------------------------------------------------------------------
// K1: blocks [0,NROWS) build CSR rows (ballot-compaction, deterministic order);
//     blocks [NROWS,2*NROWS) compute layer-1 GAT projection h1/es1/ed1.
__global__ void k1_csr_gath1(const float* __restrict__ A,
                             int* __restrict__ nbr, int* __restrict__ cnt,
                             const float* __restrict__ feats,
                             const float* __restrict__ W, const float* __restrict__ a,
                             float* __restrict__ hbuf, float* __restrict__ es,
                             float* __restrict__ ed) {
    const int lane = threadIdx.x;            // 64
    if (blockIdx.x < NROWS) {
        const int row = blockIdx.x;          // t*N + n
        const float* Ar = A + (size_t)row * NNODES;
        int* outp = nbr + (size_t)row * CAP;
        int c = 0;
        for (int j0 = 0; j0 < NNODES; j0 += 64) {
            int j = j0 + lane;
            bool p = (j < NNODES) && (Ar[j] > 0.0f);
            unsigned long long m = __ballot(p);
            int off = __popcll(m & ((1ull << lane) - 1ull));
            if (p) { int pos = c + off; if (pos < CAP) outp[pos] = j; }
            c += (int)__popcll(m);
        }
        if (lane == 0) cnt[row] = (c > CAP ? CAP : c);
    } else {
        const int b = blockIdx.x - NROWS;    // t*N + n
        const int t = b / NNODES, n = b % NNODES;
        constexpr int F = 32, D = 16;
        const int h = lane / D, d = lane % D;
        const float* xr = feats + (size_t)b * F;
        const float* Wp = W + (size_t)h * F * D + d;
        float acc = 0.f;
        #pragma unroll
        for (int f = 0; f < F; ++f) acc += xr[f] * Wp[f * D];
        hbuf[(((size_t)t * NHEADS + h) * NNODES + n) * D + d] = acc;
        float s0 = acc * a[(h * 2 + 0) * D + d];
        float s1 = acc * a[(h * 2 + 1) * D + d];
        #pragma unroll
        for (int s = D / 2; s > 0; s >>= 1) {
            s0 += __shfl_down(s0, s, D);
            s1 += __shfl_down(s1, s, D);
        }
        if (d == 0) {
            es[((size_t)t * NHEADS + h) * NNODES + n] = s0;
            ed[((size_t)t * NHEADS + h) * NNODES + n] = s1;
        }
    }
}

// ---------------------------------------------------------------------------
// Layer-2 GAT projection for all t. Grid = NROWS, block = 128.
template<int F, int D>
__global__ void gat_h_all_kernel(const float* __restrict__ x, const float* __restrict__ W,
                                 const float* __restrict__ a, float* __restrict__ hbuf,
                                 float* __restrict__ es, float* __restrict__ ed) {
    const int b = blockIdx.x;                // t*N + n
    const int t = b / NNODES, n = b % NNODES;
    const int tid = threadIdx.x;             // NHEADS*D
    const int h = tid / D, d = tid % D;
    const float* xr = x + (size_t)b * F;
    const float* Wp = W + (size_t)h * F * D + d;
    float acc = 0.f;
    #pragma unroll
    for (int f = 0; f < F; ++f) acc += xr[f] * Wp[f * D];
    hbuf[(((size_t)t * NHEADS + h) * NNODES + n) * D + d] = acc;
    float s0 = acc * a[(h * 2 + 0) * D + d];
    float s1 = acc * a[(h * 2 + 1) * D + d];
    #pragma unroll
    for (int s = D / 2; s > 0; s >>= 1) {
        s0 += __shfl_down(s0, s, D);
        s1 += __shfl_down(s1, s, D);
    }
    if (d == 0) {
        es[((size_t)t * NHEADS + h) * NNODES + n] = s0;
        ed[((size_t)t * NHEADS + h) * NNODES + n] = s1;
    }
}

// ---------------------------------------------------------------------------
// Sparse masked softmax + aggregate, all t (exact: masked entries give
// exp(-1e9-max)==0 in f32). Grid = NROWS, block = H*D.
template<int D, bool CONCAT>
__global__ void gat_attn_all_kernel(const int* __restrict__ nbr, const int* __restrict__ cnt_arr,
                                    const float* __restrict__ hbuf, const float* __restrict__ es,
                                    const float* __restrict__ ed, float* __restrict__ Z) {
    const int b = blockIdx.x;
    const int t = b / NNODES, n = b % NNODES;
    const int tid = threadIdx.x;
    const int h = tid / D, d = tid % D;
    const int cnt = cnt_arr[b];
    const int* idx = nbr + (size_t)b * CAP;
    const float* esb = es + (size_t)t * NHEADS * NNODES;
    const float* edb = ed + (size_t)t * NHEADS * NNODES;
    const float* hb  = hbuf + (size_t)t * NHEADS * NNODES * D;
    __shared__ int mlist[CAP];
    __shared__ float eds[NHEADS][CAP];
    for (int k = tid; k < cnt; k += NHEADS * D) mlist[k] = idx[k];
    __syncthreads();
    for (int k = d; k < cnt; k += D) eds[h][k] = edb[(size_t)h * NNODES + mlist[k]];
    __syncthreads();
    const float esv = esb[(size_t)h * NNODES + n];
    float maxv = -1e30f;
    for (int k = 0; k < cnt; ++k) {
        float v = esv + eds[h][k];
        v = v > 0.f ? v : 0.2f * v;          // leaky_relu(0.2)
        maxv = fmaxf(maxv, v);
    }
    float wsum = 0.f, acc = 0.f;
    for (int k = 0; k < cnt; ++k) {
        float v = esv + eds[h][k];
        v = v > 0.f ? v : 0.2f * v;
        float w = __expf(v - maxv);
        wsum += w;
        acc += w * hb[((size_t)h * NNODES + mlist[k]) * D + d];
    }
    float o = acc / wsum;
    if constexpr (CONCAT) {
        float e = o > 0.f ? o : (__expf(o) - 1.0f);       // elu
        Z[(size_t)b * (NHEADS * D) + h * D + d] = e;      // [T][N][H*D]
    } else {
        __shared__ float red[NHEADS][D];
        red[h][d] = o;
        __syncthreads();
        if (h == 0) Z[(size_t)b * D + d] =
            (red[0][d] + red[1][d] + red[2][d] + red[3][d]) * 0.25f;  // mean heads, no elu
    }
}

// ---------------------------------------------------------------------------
// Fused per-node GRU, row-segment decomposition (DS-pipe-minimal).
// Thread owns a 16-column segment of one matrix row: QUADS = D/16 lanes per row.
// Dot = 16 register FMAs + log2(QUADS) shuffles (vs 4-deep butterflies before).
// W streamed (8-t reuse), U register-resident, wz kept in LDS; weights touch
// HBM exactly once. Grid = N blocks, block = QUADS*D threads.
template<int D>
__global__ void wzgru_kernel(const float* __restrict__ Wg, const float* __restrict__ Ug,
                             const float* __restrict__ bg, const float* __restrict__ Z,
                             const float* __restrict__ q0, float* __restrict__ outp) {
    constexpr int QUADS = D / 16;            // lanes per row: 4 (D=64) or 2 (D=32)
    constexpr int TPB = QUADS * D;           // 256 or 64
    const int n = blockIdx.x, tid = threadIdx.x;
    const int quad = tid & (QUADS - 1);
    const int row  = tid / QUADS;
    const int cbase = quad * 16;
    __shared__ float Zs[TSTEPS][D];
    __shared__ float wzs[3][TSTEPS][D];
    __shared__ float Qs[D], rq[D];

    // Load Z (all t) into LDS as float4
    for (int idx = tid; idx < TSTEPS * D / 4; idx += TPB) {
        int t = idx / (D / 4), i4 = idx % (D / 4);
        reinterpret_cast<float4*>(&Zs[t][0])[i4] =
            reinterpret_cast<const float4*>(Z + ((size_t)t * NNODES + n) * D)[i4];
    }
    if (tid < D) Qs[tid] = q0[(size_t)n * D + tid];
    // Per-thread bias for its row
    float bgv[3];
    #pragma unroll
    for (int g = 0; g < 3; ++g) bgv[g] = bg[((size_t)g * NNODES + n) * D + row];
    // W row segments -> registers (streamed: dead after wz phase)
    float wseg[3][16];
    #pragma unroll
    for (int g = 0; g < 3; ++g) {
        const float4* W4 = reinterpret_cast<const float4*>(
            Wg + ((size_t)g * NNODES + n) * D * D + (size_t)row * D + cbase);
        #pragma unroll
        for (int c = 0; c < 4; ++c) {
            float4 v = W4[c];
            wseg[g][c * 4 + 0] = v.x; wseg[g][c * 4 + 1] = v.y;
            wseg[g][c * 4 + 2] = v.z; wseg[g][c * 4 + 3] = v.w;
        }
    }
    __syncthreads();   // Zs, Qs ready

    // wz[g][t][row] = W[g][row]·Z[t] + b[g][row]
    #pragma unroll
    for (int t = 0; t < TSTEPS; ++t) {
        float z16[16];
        #pragma unroll
        for (int c = 0; c < 4; ++c) {
            float4 v = reinterpret_cast<const float4*>(&Zs[t][cbase])[c];
            z16[c * 4 + 0] = v.x; z16[c * 4 + 1] = v.y;
            z16[c * 4 + 2] = v.z; z16[c * 4 + 3] = v.w;
        }
        #pragma unroll
        for (int g = 0; g < 3; ++g) {
            float p = 0.f;
            #pragma unroll
            for (int c = 0; c < 16; ++c) p += wseg[g][c] * z16[c];
            if constexpr (QUADS == 4) { p += __shfl_xor(p, 1, 4); p += __shfl_xor(p, 2, 4); }
            else                      { p += __shfl_xor(p, 1, 2); }
            if (quad == 0) wzs[g][t][row] = p + bgv[g];
        }
    }

    // U row segments -> registers (loads overlap the barrier below)
    float useg[3][16];
    #pragma unroll
    for (int g = 0; g < 3; ++g) {
        const float4* U4 = reinterpret_cast<const float4*>(
            Ug + ((size_t)g * NNODES + n) * D * D + (size_t)row * D + cbase);
        #pragma unroll
        for (int c = 0; c < 4; ++c) {
            float4 v = U4[c];
            useg[g][c * 4 + 0] = v.x; useg[g][c * 4 + 1] = v.y;
            useg[g][c * 4 + 2] = v.z; useg[g][c * 4 + 3] = v.w;
        }
    }
    __syncthreads();   // wzs ready

    // 8 sequential GRU steps; 2 barriers/step, ~20 DS-ops/thread/step
    for (int t = 0; t < TSTEPS; ++t) {
        float q16[16];
        #pragma unroll
        for (int c = 0; c < 4; ++c) {
            float4 v = reinterpret_cast<const float4*>(&Qs[cbase])[c];
            q16[c * 4 + 0] = v.x; q16[c * 4 + 1] = v.y;
            q16[c * 4 + 2] = v.z; q16[c * 4 + 3] = v.w;
        }
        float p0 = 0.f, p1 = 0.f;
        #pragma unroll
        for (int c = 0; c < 16; ++c) { p0 += useg[0][c] * q16[c]; p1 += useg[1][c] * q16[c]; }
        if constexpr (QUADS == 4) {
            p0 += __shfl_xor(p0, 1, 4); p0 += __shfl_xor(p0, 2, 4);
            p1 += __shfl_xor(p1, 1, 4); p1 += __shfl_xor(p1, 2, 4);
        } else {
            p0 += __shfl_xor(p0, 1, 2); p1 += __shfl_xor(p1, 1, 2);
        }
        const float qrow = Qs[row];
        const float zg = 1.f / (1.f + __expf(-(wzs[0][t][row] + p0)));
        const float rg = 1.f / (1.f + __expf(-(wzs[1][t][row] + p1)));
        if (quad == 0) rq[row] = rg * qrow;
        __syncthreads();
        float p2 = 0.f;
        {
            float r16[16];
            #pragma unroll
            for (int c = 0; c < 4; ++c) {
                float4 v = reinterpret_cast<const float4*>(&rq[cbase])[c];
                r16[c * 4 + 0] = v.x; r16[c * 4 + 1] = v.y;
                r16[c * 4 + 2] = v.z; r16[c * 4 + 3] = v.w;
            }
            #pragma unroll
            for (int c = 0; c < 16; ++c) p2 += useg[2][c] * r16[c];
        }
        if constexpr (QUADS == 4) { p2 += __shfl_xor(p2, 1, 4); p2 += __shfl_xor(p2, 2, 4); }
        else                      { p2 += __shfl_xor(p2, 1, 2); }
        const float hcap = tanhf(wzs[2][t][row] + p2);
        const float qn = (1.f - zg) * qrow + zg * hcap;
        if (quad == 0) {
            Qs[row] = qn;
            outp[((size_t)t * NNODES + n) * D + row] = qn;
        }
        __syncthreads();
    }
}

// ---------------------------------------------------------------------------
extern "C" void kernel_launch(void* const* d_in, const int* in_sizes, int n_in,
                              void* d_out, int out_size, void* d_ws, size_t ws_size,
                              hipStream_t stream) {
    const float* A      = (const float*)d_in[0];
    const float* feats  = (const float*)d_in[1];
    const float* gat1_W = (const float*)d_in[2];
    const float* gat1_a = (const float*)d_in[3];
    const float* gru1_W = (const float*)d_in[4];
    const float* gru1_U = (const float*)d_in[5];
    const float* gru1_b = (const float*)d_in[6];
    const float* q1     = (const float*)d_in[7];
    const float* gat2_W = (const float*)d_in[8];
    const float* gat2_a = (const float*)d_in[9];
    const float* gru2_W = (const float*)d_in[10];
    const float* gru2_U = (const float*)d_in[11];
    const float* gru2_b = (const float*)d_in[12];
    const float* q2     = (const float*)d_in[13];
    float* out = (float*)d_out;

    // Workspace layout (~30 MB)
    char* ws = (char*)d_ws;
    int*   nbr  = (int*)ws;    ws += (size_t)NROWS * CAP * 4;
    int*   cnt  = (int*)ws;    ws += (size_t)NROWS * 4;
    float* h1   = (float*)ws;  ws += (size_t)TSTEPS * NHEADS * NNODES * 16 * 4;
    float* es1  = (float*)ws;  ws += (size_t)TSTEPS * NHEADS * NNODES * 4;
    float* ed1  = (float*)ws;  ws += (size_t)TSTEPS * NHEADS * NNODES * 4;
    float* Z1   = (float*)ws;  ws += (size_t)TSTEPS * NNODES * 64 * 4;
    float* s1   = (float*)ws;  ws += (size_t)TSTEPS * NNODES * 64 * 4;
    float* h2   = (float*)ws;  ws += (size_t)TSTEPS * NHEADS * NNODES * 32 * 4;
    float* es2  = (float*)ws;  ws += (size_t)TSTEPS * NHEADS * NNODES * 4;
    float* ed2  = (float*)ws;  ws += (size_t)TSTEPS * NHEADS * NNODES * 4;
    float* Z2   = (float*)ws;  ws += (size_t)TSTEPS * NNODES * 32 * 4;

    // K1: CSR build (HBM-bound A-scan) overlapped with layer-1 GAT projection
    k1_csr_gath1<<<2 * NROWS, 64, 0, stream>>>(A, nbr, cnt, feats, gat1_W, gat1_a,
                                               h1, es1, ed1);
    // K2: layer-1 sparse attention -> Z1
    gat_attn_all_kernel<16, true><<<NROWS, 64, 0, stream>>>(nbr, cnt, h1, es1, ed1, Z1);
    // K3: layer-1 fused wz+GRU -> s1
    wzgru_kernel<64><<<NNODES, 256, 0, stream>>>(gru1_W, gru1_U, gru1_b, Z1, q1, s1);
    // K4: layer-2 GAT projection
    gat_h_all_kernel<64, 32><<<NROWS, 128, 0, stream>>>(s1, gat2_W, gat2_a, h2, es2, ed2);
    // K5: layer-2 sparse attention -> Z2
    gat_attn_all_kernel<32, false><<<NROWS, 128, 0, stream>>>(nbr, cnt, h2, es2, ed2, Z2);
    // K6: layer-2 fused wz+GRU -> out
    wzgru_kernel<32><<<NNODES, 64, 0, stream>>>(gru2_W, gru2_U, gru2_b, Z2, q2, out);
}